// Round 7
// baseline (690.485 us; speedup 1.0000x reference)
//
#include <hip/hip_runtime.h>
#include <math.h>

#define Bn 16
#define Cn 64
#define NPIX 16384
#define HIDN 4

typedef unsigned short ushort_t;
typedef short bf16x8 __attribute__((ext_vector_type(8)));
typedef float f32x4 __attribute__((ext_vector_type(4)));
#define MFMA16 __builtin_amdgcn_mfma_f32_16x16x32_bf16

// workspace offsets (floats). h stored as two bf16 planes (hi, lo), pixel-major
// [b][pix][c]: hi = ushort[0 .. 16.7M), lo = ushort[16.7M .. 33.5M)  (== 16.7M floats)
#define WS_W2B   16777216           // 64*4
#define WS_G0    (WS_W2B + 256)
#define WS_XM    (WS_G0 + 32)
#define WS_WTS   (WS_XM + 16)       // 4*16*64*6
#define WS_AP    (WS_WTS + 24576)   // 16*4*64*64
#define WS_BANDS (WS_AP + 262144)
#define WS_CORR  (WS_BANDS + 262144)
#define WS_FC2S  (WS_CORR + 262144) // fc2 bf16 hi[128*64] + lo[128*64] = 8192 floats
#define WS_W0S   (WS_FC2S + 8192)   // (W0+I) bf16 hi[4*64*64] + lo = 16384 floats
#define HLO_OFF  16777216           // ushort offset of lo plane

__device__ __forceinline__ float mishf(float t) {
    float a = 1.0f + expf(fminf(t, 40.0f));
    a = a * a;
    return t * (a - 1.0f) / (a + 1.0f);
}

// round-to-nearest-even fp32 -> bf16 split: x ~= hi + lo
__device__ __forceinline__ void split_bf16(float x, ushort_t& hi, ushort_t& lo) {
    unsigned u = __float_as_uint(x);
    unsigned r = (u + 0x7FFFu + ((u >> 16) & 1u)) >> 16;
    hi = (ushort_t)r;
    float hf = __uint_as_float(r << 16);
    float l = x - hf;
    unsigned ul = __float_as_uint(l);
    lo = (ushort_t)((ul + 0x7FFFu + ((ul >> 16) & 1u)) >> 16);
}

__device__ __forceinline__ float bflo_f(unsigned u) { return __uint_as_float(u << 16); }
__device__ __forceinline__ float bfhi_f(unsigned u) { return __uint_as_float(u & 0xffff0000u); }

// ---- tiny prep: W2 = fc1@fc0 (+bias), g0 = label.Wg ----
__global__ void prep_kernel(const float* __restrict__ fc0_w, const float* __restrict__ fc0_b,
                            const float* __restrict__ fc1_w, const float* __restrict__ fc1_b,
                            const float* __restrict__ label, const float* __restrict__ Wg,
                            float* __restrict__ ws) {
    int t = threadIdx.x;
    if (t < 64) {
        int c = t;
        float a0 = 0.f, a1 = 0.f, a2 = 0.f, ab = 0.f;
        for (int k = 0; k < 64; ++k) {
            float f = fc1_w[c * 64 + k];
            a0 += f * fc0_w[k * 3 + 0];
            a1 += f * fc0_w[k * 3 + 1];
            a2 += f * fc0_w[k * 3 + 2];
            ab += f * fc0_b[k];
        }
        ws[WS_W2B + c * 4 + 0] = a0;
        ws[WS_W2B + c * 4 + 1] = a1;
        ws[WS_W2B + c * 4 + 2] = a2;
        ws[WS_W2B + c * 4 + 3] = ab + fc1_b[c];
    } else if (t < 96) {
        int idx = t - 64;
        int hd = idx >> 3, e = idx & 7;
        float s = 0.f;
        for (int l = 0; l < 8; ++l) s += label[l] * Wg[(hd * 8 + l) * 8 + e];
        ws[WS_G0 + idx] = s;
    }
}

// ---- pre-split weights to bf16 hi/lo (once) ----
__global__ void wsplit_kernel(const float* __restrict__ w0_w, const float* __restrict__ fc2_w,
                              float* __restrict__ ws) {
    int gid = blockIdx.x * 256 + threadIdx.x;   // 96*256 = 24576
    ushort_t* w0hi = (ushort_t*)(ws + WS_W0S);
    ushort_t* w0lo = w0hi + 16384;
    ushort_t* fc2hi = (ushort_t*)(ws + WS_FC2S);
    ushort_t* fc2lo = fc2hi + 8192;
    if (gid < 16384) {
        int o = (gid >> 6) & 63, i = gid & 63;
        float v = w0_w[gid] + ((o == i) ? 1.0f : 0.0f);   // W0 + I (residual folded)
        ushort_t h, l; split_bf16(v, h, l);
        w0hi[gid] = h; w0lo[gid] = l;
    } else if (gid < 24576) {
        int k = gid - 16384;
        ushort_t h, l; split_bf16(fc2_w[k], h, l);
        fc2hi[k] = h; fc2lo[k] = l;
    }
}

// ---- xmean[b] ----
__global__ void xmean_kernel(const float* __restrict__ x, float* __restrict__ ws) {
    int b = blockIdx.x, t = threadIdx.x;
    float s = 0.f;
    for (int i = t; i < NPIX; i += 256) s += x[b * NPIX + i];
    for (int off = 32; off > 0; off >>= 1) s += __shfl_down(s, off);
    __shared__ float ps[4];
    if ((t & 63) == 0) ps[t >> 6] = s;
    __syncthreads();
    if (t == 0) ws[WS_XM + b] = (ps[0] + ps[1] + ps[2] + ps[3]) * (1.0f / NPIX);
}

// ---- gates: wts[hd][b][c][6] ----
__global__ void gates_kernel(const float* __restrict__ vg, float* __restrict__ ws) {
    int b = blockIdx.x, t = threadIdx.x;
    int c = t & 63, hd = t >> 6;
    const float* W2 = ws + WS_W2B + c * 4;
    float pooled = W2[0] * ws[WS_XM + b] + 0.5f * (W2[1] + W2[2]) + W2[3];
    float lg[8], m = -1e30f;
    for (int e = 0; e < 8; ++e) {
        lg[e] = ws[WS_G0 + hd * 8 + e] + pooled * vg[hd * 8 + e];
        m = fmaxf(m, lg[e]);
    }
    float s = 0.f;
    for (int e = 0; e < 8; ++e) { lg[e] = expf(lg[e] - m); s += lg[e]; }
    float inv = 1.0f / s;
    float* o = ws + WS_WTS + ((hd * 16 + b) * 64 + c) * 6;
    o[0] = lg[0] * inv; o[1] = lg[1] * inv; o[2] = lg[2] * inv;
    o[3] = lg[3] * inv; o[4] = (lg[4] + lg[6]) * inv; o[5] = (lg[5] + lg[7]) * inv;
}

// ---- stem: h = W2.[x,gx,gy] + b2, written as bf16 hi/lo pixel-major ----
__global__ void __launch_bounds__(256) h1_kernel(const float* __restrict__ x,
                                                 float* __restrict__ ws) {
    int gid = blockIdx.x * 256 + threadIdx.x;    // 1024 blocks -> 262144 pixels
    int pix = gid & 16383;
    int p = pix >> 7, q = pix & 127;
    __shared__ float W2s[256];
    W2s[threadIdx.x] = ws[WS_W2B + threadIdx.x];
    __syncthreads();
    float xv = x[gid];
    float gx = p * (1.0f / 127.0f), gy = q * (1.0f / 127.0f);
    ushort_t* hh = (ushort_t*)ws + (size_t)gid * 64;
    ushort_t* hl = (ushort_t*)ws + HLO_OFF + (size_t)gid * 64;
    #pragma unroll
    for (int cg = 0; cg < 8; ++cg) {
        unsigned hp[4], lp[4];
        #pragma unroll
        for (int j = 0; j < 4; ++j) {
            int c0 = (cg * 8 + 2 * j) * 4;
            float v0 = W2s[c0] * xv + W2s[c0 + 1] * gx + W2s[c0 + 2] * gy + W2s[c0 + 3];
            float v1 = W2s[c0 + 4] * xv + W2s[c0 + 5] * gx + W2s[c0 + 6] * gy + W2s[c0 + 7];
            ushort_t a0, b0, a1, b1;
            split_bf16(v0, a0, b0); split_bf16(v1, a1, b1);
            hp[j] = (unsigned)a0 | ((unsigned)a1 << 16);
            lp[j] = (unsigned)b0 | ((unsigned)b1 << 16);
        }
        *(uint4*)(hh + cg * 8) = make_uint4(hp[0], hp[1], hp[2], hp[3]);
        *(uint4*)(hl + cg * 8) = make_uint4(lp[0], lp[1], lp[2], lp[3]);
    }
}

// ---- per-layer: effective mixing matrices A'[b][k][i][o] ----
__global__ void ap_kernel(const float* __restrict__ exp_w, float* __restrict__ ws, int hd) {
    int flat = blockIdx.x * 256 + threadIdx.x;     // 2^18
    int o = flat & 63;
    int i = (flat >> 6) & 63;
    int k = (flat >> 12) & 3;
    int b = flat >> 14;
    float acc = (i == o) ? -1.0f : 0.0f;
    const float* w = ws + WS_WTS + ((hd * 16 + b) * 64 + o) * 6;
    const float* ew = exp_w + (size_t)((hd * 8) * 4 + k) * 4096 + i * 64 + o;
    #pragma unroll
    for (int e = 0; e < 6; ++e) acc += w[e] * ew[(size_t)e * 16384];
    ws[WS_AP + flat] = acc;
}

// ---- per-layer: coarsest bands from pixel-major bf16 h (shfl reduction) ----
__global__ void __launch_bounds__(256) bands_kernel(float* __restrict__ ws) {
    int bi = blockIdx.x;            // 1024 = b*64 + blk
    int b = bi >> 6, blk = bi & 63;
    int X = blk >> 3, Y = blk & 7;
    int t = threadIdx.x;
    int w = t >> 6;
    int rl = t >> 4, cl = t & 15;   // pixel within 16x16 block
    size_t pix = (size_t)b * 16384 + (X * 16 + rl) * 128 + Y * 16 + cl;
    const ushort_t* hh = (const ushort_t*)ws + pix * 64;
    const ushort_t* hl = (const ushort_t*)ws + HLO_OFF + pix * 64;
    float sj = (cl & 8) ? -1.f : 1.f;
    __shared__ float P0[4][64], P1[4][64];
    for (int cg = 0; cg < 8; ++cg) {
        uint4 hu = *(const uint4*)(hh + cg * 8);
        uint4 lu = *(const uint4*)(hl + cg * 8);
        const unsigned* hp = (const unsigned*)&hu;
        const unsigned* lp = (const unsigned*)&lu;
        #pragma unroll
        for (int j = 0; j < 4; ++j) {
            float v0 = bflo_f(hp[j]) + bflo_f(lp[j]);
            float v1 = bfhi_f(hp[j]) + bfhi_f(lp[j]);
            float s00 = v0, s10 = v0 * sj, s01 = v1, s11 = v1 * sj;
            #pragma unroll
            for (int off = 1; off < 64; off <<= 1) {
                s00 += __shfl_xor(s00, off);
                s10 += __shfl_xor(s10, off);
                s01 += __shfl_xor(s01, off);
                s11 += __shfl_xor(s11, off);
            }
            if ((t & 63) == 0) {
                int c = cg * 8 + 2 * j;
                P0[w][c] = s00; P1[w][c] = s10;
                P0[w][c + 1] = s01; P1[w][c + 1] = s11;
            }
        }
    }
    __syncthreads();
    // waves 0,1 = rows 0-7 (top, +), waves 2,3 = rows 8-15 (bottom, -)
    int c = t & 63, k = t >> 6;
    float r;
    if (k == 0)      r = P0[0][c] + P0[1][c] + P0[2][c] + P0[3][c];
    else if (k == 1) r = P1[0][c] + P1[1][c] + P1[2][c] + P1[3][c];
    else if (k == 2) r = P0[0][c] + P0[1][c] - P0[2][c] - P0[3][c];
    else             r = P1[0][c] + P1[1][c] - P1[2][c] - P1[3][c];
    ws[WS_BANDS + (size_t)b * 16384 + k * 4096 + c * 64 + X * 8 + Y] = r * 0.0625f;
}

// ---- per-layer: corr[b][k][o][xy] = sum_i A'[b][k][i][o] * bands[b][k][i][xy] ----
__global__ void mix_kernel(float* __restrict__ ws) {
    int bi = blockIdx.x;            // 64 = b*4+k
    int t = threadIdx.x;
    __shared__ float sA[64][65];
    __shared__ float sB[64][64];
    const float* Ap = ws + WS_AP + (size_t)bi * 4096;
    const float* Bd = ws + WS_BANDS + (size_t)bi * 4096;
    for (int it = 0; it < 16; ++it) {
        int flat = it * 256 + t;
        sA[flat >> 6][flat & 63] = Ap[flat];
        sB[flat >> 6][flat & 63] = Bd[flat];
    }
    __syncthreads();
    int xy = t & 63, ob = (t >> 6) * 16;
    float acc[16];
    #pragma unroll
    for (int j = 0; j < 16; ++j) acc[j] = 0.f;
    for (int i = 0; i < 64; ++i) {
        float v = sB[i][xy];
        #pragma unroll
        for (int j = 0; j < 16; ++j) acc[j] = fmaf(sA[i][ob + j], v, acc[j]);
    }
    float* out = ws + WS_CORR + (size_t)bi * 4096 + xy;
    #pragma unroll
    for (int j = 0; j < 16; ++j) out[(ob + j) * 64] = acc[j];
}

// ---- per-layer main (MFMA): h = act((W0+I)h + b0 + U(corr)) in place ----
// A/B fragments direct from global pre-split bf16; LDS only for corr table.
__global__ void __launch_bounds__(256) conv_mfma(float* __restrict__ ws,
        const float* __restrict__ w0_b, int hd, int act) {
    int bi = blockIdx.x;            // 1024 = b*64 + seg; block = 256 px (2 rows)
    int b = bi >> 6, seg = bi & 63;
    int t = threadIdx.x;
    __shared__ float sCorr[64][17];
    {
        int X = seg >> 3;
        float si = ((seg >> 2) & 1) ? -1.f : 1.f;
        #pragma unroll
        for (int rep = 0; rep < 4; ++rep) {
            int idx = rep * 256 + t;
            int o = idx >> 4, oct = idx & 15;
            int Yc = oct >> 1;
            float sj = (oct & 1) ? -1.f : 1.f;
            const float* cb = ws + WS_CORR + (size_t)b * 16384 + o * 64 + X * 8 + Yc;
            sCorr[o][oct] = w0_b[hd * 64 + o] +
                0.0625f * (cb[0] + sj * cb[4096] + si * cb[8192] + si * sj * cb[12288]);
        }
    }
    __syncthreads();
    int w = t >> 6, l = t & 63, lr = l & 15, lk = l >> 4;
    const ushort_t* w0hi = (const ushort_t*)(ws + WS_W0S) + hd * 4096;
    const ushort_t* w0lo = w0hi + 16384;
    bf16x8 Ah[4][2], Al[4][2];
    #pragma unroll
    for (int m = 0; m < 4; ++m) {
        const ushort_t* rp = w0hi + (16 * m + lr) * 64 + 8 * lk;
        Ah[m][0] = *(const bf16x8*)rp;
        Ah[m][1] = *(const bf16x8*)(rp + 32);
        const ushort_t* rpl = w0lo + (16 * m + lr) * 64 + 8 * lk;
        Al[m][0] = *(const bf16x8*)rpl;
        Al[m][1] = *(const bf16x8*)(rpl + 32);
    }
    ushort_t* Hhi = (ushort_t*)ws;
    ushort_t* Hlo = Hhi + HLO_OFF;
    #pragma unroll
    for (int pt = 0; pt < 4; ++pt) {
        int poff = 64 * w + 16 * pt + lr;                    // 0..255 within block
        size_t pixg = (size_t)(b * 16384 + seg * 256 + poff);
        const ushort_t* bp = Hhi + pixg * 64 + 8 * lk;
        const ushort_t* bpl = Hlo + pixg * 64 + 8 * lk;
        bf16x8 Bh0 = *(const bf16x8*)bp;
        bf16x8 Bh1 = *(const bf16x8*)(bp + 32);
        bf16x8 Bl0 = *(const bf16x8*)bpl;
        bf16x8 Bl1 = *(const bf16x8*)(bpl + 32);
        int oct = (poff & 127) >> 3;
        #pragma unroll
        for (int m = 0; m < 4; ++m) {
            f32x4 a = {0.f, 0.f, 0.f, 0.f};
            a = MFMA16(Ah[m][0], Bh0, a, 0, 0, 0);
            a = MFMA16(Ah[m][1], Bh1, a, 0, 0, 0);
            a = MFMA16(Ah[m][0], Bl0, a, 0, 0, 0);
            a = MFMA16(Ah[m][1], Bl1, a, 0, 0, 0);
            a = MFMA16(Al[m][0], Bh0, a, 0, 0, 0);
            a = MFMA16(Al[m][1], Bh1, a, 0, 0, 0);
            int o0 = 16 * m + 4 * lk;
            float v0 = a[0] + sCorr[o0 + 0][oct];
            float v1 = a[1] + sCorr[o0 + 1][oct];
            float v2 = a[2] + sCorr[o0 + 2][oct];
            float v3 = a[3] + sCorr[o0 + 3][oct];
            if (act) { v0 = mishf(v0); v1 = mishf(v1); v2 = mishf(v2); v3 = mishf(v3); }
            ushort_t h0, q0, h1, q1, h2, q2, h3, q3;
            split_bf16(v0, h0, q0); split_bf16(v1, h1, q1);
            split_bf16(v2, h2, q2); split_bf16(v3, h3, q3);
            uint2 hv = make_uint2((unsigned)h0 | ((unsigned)h1 << 16),
                                  (unsigned)h2 | ((unsigned)h3 << 16));
            uint2 lv = make_uint2((unsigned)q0 | ((unsigned)q1 << 16),
                                  (unsigned)q2 | ((unsigned)q3 << 16));
            *(uint2*)(Hhi + pixg * 64 + o0) = hv;
            *(uint2*)(Hlo + pixg * 64 + o0) = lv;
        }
    }
}

// ---- final (MFMA): out = fc3 . mish(fc2 h + b2f) + b3 ----
__global__ void __launch_bounds__(256) final_mfma(const float* __restrict__ ws,
        const float* __restrict__ fc2_b, const float* __restrict__ fc3_w,
        const float* __restrict__ fc3_b, float* __restrict__ out) {
    int bi = blockIdx.x;            // 1024
    int b = bi >> 6, seg = bi & 63;
    int t = threadIdx.x;
    __shared__ float sB2[128], sF3[128];
    if (t < 128) { sB2[t] = fc2_b[t]; sF3[t] = fc3_w[t]; }
    __syncthreads();
    int w = t >> 6, l = t & 63, lr = l & 15, lk = l >> 4;
    const ushort_t* fc2hi = (const ushort_t*)(ws + WS_FC2S);
    const ushort_t* fc2lo = fc2hi + 8192;
    const ushort_t* Hhi = (const ushort_t*)ws;
    const ushort_t* Hlo = Hhi + HLO_OFF;
    int pbase = b * 16384 + seg * 256 + 64 * w;
    bf16x8 Bh[4][2], Bl[4][2];
    #pragma unroll
    for (int pt = 0; pt < 4; ++pt) {
        size_t pg = (size_t)(pbase + 16 * pt + lr);
        const ushort_t* bp = Hhi + pg * 64 + 8 * lk;
        Bh[pt][0] = *(const bf16x8*)bp;
        Bh[pt][1] = *(const bf16x8*)(bp + 32);
        const ushort_t* bpl = Hlo + pg * 64 + 8 * lk;
        Bl[pt][0] = *(const bf16x8*)bpl;
        Bl[pt][1] = *(const bf16x8*)(bpl + 32);
    }
    float part[4] = {0.f, 0.f, 0.f, 0.f};
    #pragma unroll
    for (int m = 0; m < 8; ++m) {
        const ushort_t* rp = fc2hi + (16 * m + lr) * 64 + 8 * lk;
        bf16x8 Ah0 = *(const bf16x8*)rp, Ah1 = *(const bf16x8*)(rp + 32);
        const ushort_t* rpl = fc2lo + (16 * m + lr) * 64 + 8 * lk;
        bf16x8 Al0 = *(const bf16x8*)rpl, Al1 = *(const bf16x8*)(rpl + 32);
        int j0 = 16 * m + 4 * lk;
        float c0 = sB2[j0], c1 = sB2[j0 + 1], c2 = sB2[j0 + 2], c3 = sB2[j0 + 3];
        float f0 = sF3[j0], f1 = sF3[j0 + 1], f2 = sF3[j0 + 2], f3 = sF3[j0 + 3];
        #pragma unroll
        for (int pt = 0; pt < 4; ++pt) {
            f32x4 a = {0.f, 0.f, 0.f, 0.f};
            a = MFMA16(Ah0, Bh[pt][0], a, 0, 0, 0);
            a = MFMA16(Ah1, Bh[pt][1], a, 0, 0, 0);
            a = MFMA16(Ah0, Bl[pt][0], a, 0, 0, 0);
            a = MFMA16(Ah1, Bl[pt][1], a, 0, 0, 0);
            a = MFMA16(Al0, Bh[pt][0], a, 0, 0, 0);
            a = MFMA16(Al1, Bh[pt][1], a, 0, 0, 0);
            part[pt] += f0 * mishf(a[0] + c0) + f1 * mishf(a[1] + c1)
                      + f2 * mishf(a[2] + c2) + f3 * mishf(a[3] + c3);
        }
    }
    #pragma unroll
    for (int pt = 0; pt < 4; ++pt) {
        float p = part[pt];
        p += __shfl_xor(p, 16);
        p += __shfl_xor(p, 32);
        if (lk == 0) out[(size_t)(pbase + 16 * pt + lr)] = p + fc3_b[0];
    }
}

extern "C" void kernel_launch(void* const* d_in, const int* in_sizes, int n_in,
                              void* d_out, int out_size, void* d_ws, size_t ws_size,
                              hipStream_t stream) {
    const float* x      = (const float*)d_in[0];
    const float* label  = (const float*)d_in[1];
    const float* fc0_w  = (const float*)d_in[2];
    const float* fc0_b  = (const float*)d_in[3];
    const float* fc1_w  = (const float*)d_in[4];
    const float* fc1_b  = (const float*)d_in[5];
    const float* gate_Wg = (const float*)d_in[6];
    const float* gate_vg = (const float*)d_in[7];
    const float* exp_w  = (const float*)d_in[8];
    const float* w0_w   = (const float*)d_in[9];
    const float* w0_b   = (const float*)d_in[10];
    const float* fc2_w  = (const float*)d_in[11];
    const float* fc2_b  = (const float*)d_in[12];
    const float* fc3_w  = (const float*)d_in[13];
    const float* fc3_b  = (const float*)d_in[14];
    float* out = (float*)d_out;
    float* ws = (float*)d_ws;

    prep_kernel<<<1, 256, 0, stream>>>(fc0_w, fc0_b, fc1_w, fc1_b, label, gate_Wg, ws);
    wsplit_kernel<<<96, 256, 0, stream>>>(w0_w, fc2_w, ws);
    xmean_kernel<<<16, 256, 0, stream>>>(x, ws);
    gates_kernel<<<16, 256, 0, stream>>>(gate_vg, ws);
    h1_kernel<<<1024, 256, 0, stream>>>(x, ws);
    for (int hd = 0; hd < HIDN; ++hd) {
        ap_kernel<<<1024, 256, 0, stream>>>(exp_w, ws, hd);
        bands_kernel<<<1024, 256, 0, stream>>>(ws);
        mix_kernel<<<64, 256, 0, stream>>>(ws);
        conv_mfma<<<1024, 256, 0, stream>>>(ws, w0_b, hd, hd != HIDN - 1);
    }
    final_mfma<<<1024, 256, 0, stream>>>(ws, fc2_b, fc3_w, fc3_b, out);
}

// Round 11
// 505.135 us; speedup vs baseline: 1.3669x; 1.3669x over previous
//
#include <hip/hip_runtime.h>
#include <math.h>

#define Bn 16
#define Cn 64
#define NPIX 16384
#define HIDN 4

typedef unsigned short ushort_t;
typedef short bf16x8 __attribute__((ext_vector_type(8)));
typedef float f32x4 __attribute__((ext_vector_type(4)));
#define MFMA16 __builtin_amdgcn_mfma_f32_16x16x32_bf16

// workspace offsets (floats); h fp32 channel-major [b][c][pix] at 0
#define WS_H     0
#define WS_W2B   16777216           // 64*4
#define WS_G0    (WS_W2B + 256)
#define WS_XM    (WS_G0 + 32)
#define WS_WTS   (WS_XM + 16)       // 4*16*64*6
#define WS_AP    (WS_WTS + 24576)   // 16*4*64*64
#define WS_BANDS (WS_AP + 262144)
#define WS_CORR  (WS_BANDS + 262144)
#define WS_FC2S  (WS_CORR + 262144) // fc2 bf16 hi[8192] + lo[8192] shorts = 8192 floats
#define WS_W0S   (WS_FC2S + 8192)   // (W0+I) bf16 hi[16384] + lo[16384] shorts = 16384 floats

__device__ __forceinline__ float mishf(float t) {
    float a = 1.0f + expf(fminf(t, 40.0f));
    a = a * a;
    return t * (a - 1.0f) / (a + 1.0f);
}

// RNE hi + truncated lo split: x ~= hi + lo, err ~2^-17 rel
__device__ __forceinline__ void split_bf16(float x, ushort_t& hi, ushort_t& lo) {
    unsigned u = __float_as_uint(x);
    unsigned r = (u + 0x7FFFu + ((u >> 16) & 1u)) >> 16;
    hi = (ushort_t)r;
    float l = x - __uint_as_float(r << 16);
    lo = (ushort_t)(__float_as_uint(l) >> 16);
}

// ---- tiny prep: W2 = fc1@fc0 (+bias), g0 = label.Wg ----
__global__ void prep_kernel(const float* __restrict__ fc0_w, const float* __restrict__ fc0_b,
                            const float* __restrict__ fc1_w, const float* __restrict__ fc1_b,
                            const float* __restrict__ label, const float* __restrict__ Wg,
                            float* __restrict__ ws) {
    int t = threadIdx.x;
    if (t < 64) {
        int c = t;
        float a0 = 0.f, a1 = 0.f, a2 = 0.f, ab = 0.f;
        for (int k = 0; k < 64; ++k) {
            float f = fc1_w[c * 64 + k];
            a0 += f * fc0_w[k * 3 + 0];
            a1 += f * fc0_w[k * 3 + 1];
            a2 += f * fc0_w[k * 3 + 2];
            ab += f * fc0_b[k];
        }
        ws[WS_W2B + c * 4 + 0] = a0;
        ws[WS_W2B + c * 4 + 1] = a1;
        ws[WS_W2B + c * 4 + 2] = a2;
        ws[WS_W2B + c * 4 + 3] = ab + fc1_b[c];
    } else if (t < 96) {
        int idx = t - 64;
        int hd = idx >> 3, e = idx & 7;
        float s = 0.f;
        for (int l = 0; l < 8; ++l) s += label[l] * Wg[(hd * 8 + l) * 8 + e];
        ws[WS_G0 + idx] = s;
    }
}

// ---- pre-split weights to bf16 hi/lo (once) ----
__global__ void wsplit_kernel(const float* __restrict__ w0_w, const float* __restrict__ fc2_w,
                              float* __restrict__ ws) {
    int gid = blockIdx.x * 256 + threadIdx.x;   // 96*256 = 24576
    ushort_t* w0hi = (ushort_t*)(ws + WS_W0S);
    ushort_t* w0lo = w0hi + 16384;
    ushort_t* fc2hi = (ushort_t*)(ws + WS_FC2S);
    ushort_t* fc2lo = fc2hi + 8192;
    if (gid < 16384) {
        int o = (gid >> 6) & 63, i = gid & 63;
        float v = w0_w[gid] + ((o == i) ? 1.0f : 0.0f);   // W0 + I (residual folded)
        ushort_t h, l; split_bf16(v, h, l);
        w0hi[gid] = h; w0lo[gid] = l;
    } else if (gid < 24576) {
        int k = gid - 16384;
        ushort_t h, l; split_bf16(fc2_w[k], h, l);
        fc2hi[k] = h; fc2lo[k] = l;
    }
}

// ---- xmean[b] ----
__global__ void xmean_kernel(const float* __restrict__ x, float* __restrict__ ws) {
    int b = blockIdx.x, t = threadIdx.x;
    float s = 0.f;
    for (int i = t; i < NPIX; i += 256) s += x[b * NPIX + i];
    for (int off = 32; off > 0; off >>= 1) s += __shfl_down(s, off);
    __shared__ float ps[4];
    if ((t & 63) == 0) ps[t >> 6] = s;
    __syncthreads();
    if (t == 0) ws[WS_XM + b] = (ps[0] + ps[1] + ps[2] + ps[3]) * (1.0f / NPIX);
}

// ---- gates: wts[hd][b][c][6] ----
__global__ void gates_kernel(const float* __restrict__ vg, float* __restrict__ ws) {
    int b = blockIdx.x, t = threadIdx.x;
    int c = t & 63, hd = t >> 6;
    const float* W2 = ws + WS_W2B + c * 4;
    float pooled = W2[0] * ws[WS_XM + b] + 0.5f * (W2[1] + W2[2]) + W2[3];
    float lg[8], m = -1e30f;
    for (int e = 0; e < 8; ++e) {
        lg[e] = ws[WS_G0 + hd * 8 + e] + pooled * vg[hd * 8 + e];
        m = fmaxf(m, lg[e]);
    }
    float s = 0.f;
    for (int e = 0; e < 8; ++e) { lg[e] = expf(lg[e] - m); s += lg[e]; }
    float inv = 1.0f / s;
    float* o = ws + WS_WTS + ((hd * 16 + b) * 64 + c) * 6;
    o[0] = lg[0] * inv; o[1] = lg[1] * inv; o[2] = lg[2] * inv;
    o[3] = lg[3] * inv; o[4] = (lg[4] + lg[6]) * inv; o[5] = (lg[5] + lg[7]) * inv;
}

// ---- stem: h = W2 . [x, gx, gy] + b2 (fp32 channel-major) ----
__global__ void h1_kernel(const float* __restrict__ x, float* __restrict__ ws) {
    int gid = blockIdx.x * 256 + threadIdx.x;
    int base = gid * 4;
    int b = base >> 20;
    int rem = base & 1048575;
    int c = rem >> 14;
    int pix = rem & 16383;
    int p = pix >> 7, q = pix & 127;
    const float* W2 = ws + WS_W2B + c * 4;
    float w0 = W2[0], w1 = W2[1], w2 = W2[2], bb = W2[3];
    float4 xv = *(const float4*)(x + b * NPIX + pix);
    float gx = p * (1.0f / 127.0f);
    float gy0 = q * (1.0f / 127.0f);
    const float step = 1.0f / 127.0f;
    float4 o;
    o.x = w0 * xv.x + w1 * gx + w2 * gy0 + bb;
    o.y = w0 * xv.y + w1 * gx + w2 * (gy0 + step) + bb;
    o.z = w0 * xv.z + w1 * gx + w2 * (gy0 + 2.f * step) + bb;
    o.w = w0 * xv.w + w1 * gx + w2 * (gy0 + 3.f * step) + bb;
    *(float4*)(ws + WS_H + base) = o;
}

// ---- per-layer: effective mixing matrices A'[b][k][i][o] ----
__global__ void ap_kernel(const float* __restrict__ exp_w, float* __restrict__ ws, int hd) {
    int flat = blockIdx.x * 256 + threadIdx.x;     // 2^18
    int o = flat & 63;
    int i = (flat >> 6) & 63;
    int k = (flat >> 12) & 3;
    int b = flat >> 14;
    float acc = (i == o) ? -1.0f : 0.0f;
    const float* w = ws + WS_WTS + ((hd * 16 + b) * 64 + o) * 6;
    const float* ew = exp_w + (size_t)((hd * 8) * 4 + k) * 4096 + i * 64 + o;
    #pragma unroll
    for (int e = 0; e < 6; ++e) acc += w[e] * ew[(size_t)e * 16384];
    ws[WS_AP + flat] = acc;
}

// ---- per-layer: coarsest-band extraction (coalesced fp32) ----
__global__ void bands_kernel(const float* __restrict__ hbuf, float* __restrict__ ws) {
    int bi = blockIdx.x;            // 1024
    int b = bi >> 6, c = bi & 63;
    int t = threadIdx.x;
    __shared__ float R[128][17];
    __shared__ float S[16][17];
    const float* plane = hbuf + (size_t)(b * 64 + c) * NPIX;
    for (int rb = 0; rb < 8; ++rb) {
        const float* p4 = plane + rb * 2048 + t * 8;
        float4 a = *(const float4*)p4;
        float4 bb = *(const float4*)(p4 + 4);
        R[rb * 16 + (t >> 4)][t & 15] = a.x + a.y + a.z + a.w + bb.x + bb.y + bb.z + bb.w;
    }
    __syncthreads();
    {
        int rb2 = t >> 4, g = t & 15;
        float s = 0.f;
        #pragma unroll
        for (int k = 0; k < 8; ++k) s += R[rb2 * 8 + k][g];
        S[rb2][g] = s;
    }
    __syncthreads();
    if (t < 64) {
        int X = t >> 3, Y = t & 7;
        float q00 = S[2 * X][2 * Y],     q01 = S[2 * X][2 * Y + 1];
        float q10 = S[2 * X + 1][2 * Y], q11 = S[2 * X + 1][2 * Y + 1];
        float* bd = ws + WS_BANDS + (size_t)b * 16384 + c * 64 + t;
        bd[0]     = (q00 + q01 + q10 + q11) * 0.0625f;
        bd[4096]  = (q00 - q01 + q10 - q11) * 0.0625f;
        bd[8192]  = (q00 + q01 - q10 - q11) * 0.0625f;
        bd[12288] = (q00 - q01 - q10 + q11) * 0.0625f;
    }
}

// ---- per-layer: corr[b][k][o][xy] = sum_i A'[b][k][i][o] * bands[b][k][i][xy] ----
__global__ void mix_kernel(float* __restrict__ ws) {
    int bi = blockIdx.x;            // 64 = b*4+k
    int t = threadIdx.x;
    __shared__ float sA[64][65];
    __shared__ float sB[64][64];
    const float* Ap = ws + WS_AP + (size_t)bi * 4096;
    const float* Bd = ws + WS_BANDS + (size_t)bi * 4096;
    for (int it = 0; it < 16; ++it) {
        int flat = it * 256 + t;
        sA[flat >> 6][flat & 63] = Ap[flat];
        sB[flat >> 6][flat & 63] = Bd[flat];
    }
    __syncthreads();
    int xy = t & 63, ob = (t >> 6) * 16;
    float acc[16];
    #pragma unroll
    for (int j = 0; j < 16; ++j) acc[j] = 0.f;
    for (int i = 0; i < 64; ++i) {
        float v = sB[i][xy];
        #pragma unroll
        for (int j = 0; j < 16; ++j) acc[j] = fmaf(sA[i][ob + j], v, acc[j]);
    }
    float* out = ws + WS_CORR + (size_t)bi * 4096 + xy;
    #pragma unroll
    for (int j = 0; j < 16; ++j) out[(ob + j) * 64] = acc[j];
}

// ---- per-layer main (MFMA): h = act((W0+I)h + b0 + U(corr)) in place ----
// A-fragments direct from pre-split global weights; only h-tile staged in LDS.
__global__ void __launch_bounds__(256) conv_mfma(
        float* __restrict__ hbuf, const float* __restrict__ ws,
        const float* __restrict__ w0_b, int hd, int act) {
    int bi = blockIdx.x;            // 4096
    int b = bi >> 8, r = bi & 255;
    int row = r >> 1, qh = (r & 1) * 64;
    int t = threadIdx.x;
    __shared__ short sBhi[64][72];  // h tile, [px][i]
    __shared__ short sBlo[64][72];
    __shared__ float sCorr[8][64];  // [qg][o]

    const float* hbase = hbuf + (size_t)b * 64 * NPIX + row * 128 + qh;
    {
        int px = t & 63, lane4 = t >> 6;
        for (int rep = 0; rep < 8; ++rep) {
            int c0 = rep * 8 + lane4 * 2;
            float v0 = hbase[(size_t)c0 * NPIX + px];
            float v1 = hbase[(size_t)(c0 + 1) * NPIX + px];
            ushort_t h0, l0, h1, l1;
            split_bf16(v0, h0, l0);
            split_bf16(v1, h1, l1);
            *(unsigned*)&sBhi[px][c0] = (unsigned)h0 | ((unsigned)h1 << 16);
            *(unsigned*)&sBlo[px][c0] = (unsigned)l0 | ((unsigned)l1 << 16);
        }
    }
    {
        int X = row >> 4;
        float si = ((row >> 3) & 1) ? -1.f : 1.f;
        for (int rep = 0; rep < 2; ++rep) {
            int idx = rep * 256 + t;        // 512
            int o = idx & 63, qg = idx >> 6;
            int Y = (r & 1) * 4 + (qg >> 1);
            float sj = (qg & 1) ? -1.f : 1.f;
            const float* cb = ws + WS_CORR + (size_t)b * 16384 + o * 64 + X * 8 + Y;
            sCorr[qg][o] = w0_b[hd * 64 + o] +
                           0.0625f * (cb[0] + sj * cb[4096] + si * cb[8192] + si * sj * cb[12288]);
        }
    }
    int w = t >> 6, l = t & 63;
    int lr = l & 15, lk = l >> 4;
    // A-fragments from global pre-split weights (L1/L2-hot, 16 KB total)
    const ushort_t* w0hi = (const ushort_t*)(ws + WS_W0S) + hd * 4096;
    const ushort_t* w0lo = w0hi + 16384;
    bf16x8 Ah[4][2], Al[4][2];
    #pragma unroll
    for (int m = 0; m < 4; ++m) {
        int o0 = 16 * m + lr;
        Ah[m][0] = *(const bf16x8*)(w0hi + o0 * 64 + 8 * lk);
        Ah[m][1] = *(const bf16x8*)(w0hi + o0 * 64 + 32 + 8 * lk);
        Al[m][0] = *(const bf16x8*)(w0lo + o0 * 64 + 8 * lk);
        Al[m][1] = *(const bf16x8*)(w0lo + o0 * 64 + 32 + 8 * lk);
    }
    __syncthreads();

    int px = 16 * w + lr;
    bf16x8 Bh0 = *(const bf16x8*)&sBhi[px][8 * lk];
    bf16x8 Bh1 = *(const bf16x8*)&sBhi[px][32 + 8 * lk];
    bf16x8 Bl0 = *(const bf16x8*)&sBlo[px][8 * lk];
    bf16x8 Bl1 = *(const bf16x8*)&sBlo[px][32 + 8 * lk];
    int qg = px >> 3;
    float* outp = hbuf + (size_t)(b * 64 + 4 * lk) * NPIX + row * 128 + qh + px;
    #pragma unroll
    for (int m = 0; m < 4; ++m) {
        f32x4 a = {0.f, 0.f, 0.f, 0.f};
        a = MFMA16(Ah[m][0], Bh0, a, 0, 0, 0);
        a = MFMA16(Ah[m][1], Bh1, a, 0, 0, 0);
        a = MFMA16(Ah[m][0], Bl0, a, 0, 0, 0);
        a = MFMA16(Ah[m][1], Bl1, a, 0, 0, 0);
        a = MFMA16(Al[m][0], Bh0, a, 0, 0, 0);
        a = MFMA16(Al[m][1], Bh1, a, 0, 0, 0);
        float4 c4 = *(const float4*)&sCorr[qg][16 * m + 4 * lk];
        float cv[4] = {c4.x, c4.y, c4.z, c4.w};
        #pragma unroll
        for (int rr = 0; rr < 4; ++rr) {
            float v = a[rr] + cv[rr];
            if (act) v = mishf(v);
            outp[(size_t)(16 * m + rr) * NPIX] = v;
        }
    }
}

// ---- final (MFMA): out = fc3 . mish(fc2 h + b2f) + b3 ----
__global__ void __launch_bounds__(256) final_mfma(
        const float* __restrict__ hbuf, const float* __restrict__ ws,
        const float* __restrict__ fc2_b, const float* __restrict__ fc3_w,
        const float* __restrict__ fc3_b, float* __restrict__ out) {
    int bi = blockIdx.x;            // 4096
    int b = bi >> 8, r = bi & 255;
    int row = r >> 1, qh = (r & 1) * 64;
    int t = threadIdx.x;
    __shared__ short sBhi[64][72];   // h tile [px][i]
    __shared__ short sBlo[64][72];
    __shared__ float sB2[128];
    __shared__ float sF3[128];

    const float* hbase = hbuf + (size_t)b * 64 * NPIX + row * 128 + qh;
    {
        int px = t & 63, lane4 = t >> 6;
        for (int rep = 0; rep < 8; ++rep) {
            int c0 = rep * 8 + lane4 * 2;
            float v0 = hbase[(size_t)c0 * NPIX + px];
            float v1 = hbase[(size_t)(c0 + 1) * NPIX + px];
            ushort_t h0, l0, h1, l1;
            split_bf16(v0, h0, l0);
            split_bf16(v1, h1, l1);
            *(unsigned*)&sBhi[px][c0] = (unsigned)h0 | ((unsigned)h1 << 16);
            *(unsigned*)&sBlo[px][c0] = (unsigned)l0 | ((unsigned)l1 << 16);
        }
        if (t < 128) { sB2[t] = fc2_b[t]; sF3[t] = fc3_w[t]; }
    }
    __syncthreads();

    int w = t >> 6, l = t & 63;
    int lr = l & 15, lk = l >> 4;
    int px = 16 * w + lr;
    const ushort_t* fc2hi = (const ushort_t*)(ws + WS_FC2S);
    const ushort_t* fc2lo = fc2hi + 8192;
    bf16x8 Bh0 = *(const bf16x8*)&sBhi[px][8 * lk];
    bf16x8 Bh1 = *(const bf16x8*)&sBhi[px][32 + 8 * lk];
    bf16x8 Bl0 = *(const bf16x8*)&sBlo[px][8 * lk];
    bf16x8 Bl1 = *(const bf16x8*)&sBlo[px][32 + 8 * lk];
    float partial = 0.f;
    #pragma unroll
    for (int m = 0; m < 8; ++m) {
        int j0 = 16 * m + lr;
        bf16x8 Ah0 = *(const bf16x8*)(fc2hi + j0 * 64 + 8 * lk);
        bf16x8 Ah1 = *(const bf16x8*)(fc2hi + j0 * 64 + 32 + 8 * lk);
        bf16x8 Al0 = *(const bf16x8*)(fc2lo + j0 * 64 + 8 * lk);
        bf16x8 Al1 = *(const bf16x8*)(fc2lo + j0 * 64 + 32 + 8 * lk);
        f32x4 a = {0.f, 0.f, 0.f, 0.f};
        a = MFMA16(Ah0, Bh0, a, 0, 0, 0);
        a = MFMA16(Ah1, Bh1, a, 0, 0, 0);
        a = MFMA16(Ah0, Bl0, a, 0, 0, 0);
        a = MFMA16(Ah1, Bl1, a, 0, 0, 0);
        a = MFMA16(Al0, Bh0, a, 0, 0, 0);
        a = MFMA16(Al1, Bh1, a, 0, 0, 0);
        float4 b4 = *(const float4*)&sB2[16 * m + 4 * lk];
        float4 f4 = *(const float4*)&sF3[16 * m + 4 * lk];
        float bv[4] = {b4.x, b4.y, b4.z, b4.w};
        float fv[4] = {f4.x, f4.y, f4.z, f4.w};
        #pragma unroll
        for (int rr = 0; rr < 4; ++rr)
            partial = fmaf(fv[rr], mishf(a[rr] + bv[rr]), partial);
    }
    partial += __shfl_xor(partial, 16, 64);
    partial += __shfl_xor(partial, 32, 64);
    if (lk == 0)
        out[(size_t)b * NPIX + row * 128 + qh + px] = partial + fc3_b[0];
}

extern "C" void kernel_launch(void* const* d_in, const int* in_sizes, int n_in,
                              void* d_out, int out_size, void* d_ws, size_t ws_size,
                              hipStream_t stream) {
    const float* x      = (const float*)d_in[0];
    const float* label  = (const float*)d_in[1];
    const float* fc0_w  = (const float*)d_in[2];
    const float* fc0_b  = (const float*)d_in[3];
    const float* fc1_w  = (const float*)d_in[4];
    const float* fc1_b  = (const float*)d_in[5];
    const float* gate_Wg = (const float*)d_in[6];
    const float* gate_vg = (const float*)d_in[7];
    const float* exp_w  = (const float*)d_in[8];
    const float* w0_w   = (const float*)d_in[9];
    const float* w0_b   = (const float*)d_in[10];
    const float* fc2_w  = (const float*)d_in[11];
    const float* fc2_b  = (const float*)d_in[12];
    const float* fc3_w  = (const float*)d_in[13];
    const float* fc3_b  = (const float*)d_in[14];
    float* out = (float*)d_out;
    float* ws = (float*)d_ws;
    float* hbuf = ws + WS_H;

    prep_kernel<<<1, 256, 0, stream>>>(fc0_w, fc0_b, fc1_w, fc1_b, label, gate_Wg, ws);
    wsplit_kernel<<<96, 256, 0, stream>>>(w0_w, fc2_w, ws);
    xmean_kernel<<<16, 256, 0, stream>>>(x, ws);
    gates_kernel<<<16, 256, 0, stream>>>(gate_vg, ws);
    h1_kernel<<<16384, 256, 0, stream>>>(x, ws);
    for (int hd = 0; hd < HIDN; ++hd) {
        ap_kernel<<<1024, 256, 0, stream>>>(exp_w, ws, hd);
        bands_kernel<<<1024, 256, 0, stream>>>(hbuf, ws);
        mix_kernel<<<64, 256, 0, stream>>>(ws);
        conv_mfma<<<4096, 256, 0, stream>>>(hbuf, ws, w0_b, hd, hd != HIDN - 1);
    }
    final_mfma<<<4096, 256, 0, stream>>>(hbuf, ws, fc2_b, fc3_w, fc3_b, out);
}